// Round 6
// baseline (1231.996 us; speedup 1.0000x reference)
//
#include <hip/hip_runtime.h>
#include <math.h>

#define DATA 64
#define WIDTH 256
#define BATCHN 512
#define TPTS 16
#define MAXSUB 8
#define NSAMP 2
#define NBLK (BATCHN / NSAMP)
#define NTHR 1024

#define RTOLc 1e-3f
#define ATOLc 1e-6f
#define SAFETYc 0.9f
#define FMINc 0.2f
#define FMAXc 10.0f

// Tsit5 tableau
#define A21 0.161f
#define A31 (-0.008480655492356989f)
#define A32 0.335480655492357f
#define A41 2.8971530571054935f
#define A42 (-6.359448489975075f)
#define A43 4.3622954328695815f
#define A51 5.325864828439257f
#define A52 (-11.748883564062828f)
#define A53 7.4955393428898365f
#define A54 (-0.09249506636175525f)
#define A61 5.86145544294642f
#define A62 (-12.92096931784711f)
#define A63 8.159367898576159f
#define A64 (-0.071584973281401f)
#define A65 (-0.028269050394068383f)
#define B1c 0.09646076681806523f
#define B2c 0.01f
#define B3c 0.4798896504144996f
#define B4c 1.379008574103742f
#define B5c (-3.290069515436081f)
#define B6c 2.324710524099774f
#define E1c (-0.001780011052226f)
#define E2c (-0.000816434459657f)
#define E3c 0.007880878010262f
#define E4c (-0.144711007173263f)
#define E5c 0.582357165452555f
#define E6c (-0.458082105929187f)
#define E7c 0.015151515151515152f

__device__ __forceinline__ float softplus_jax(float x) {
    // jax.nn.softplus(x) == max(x,0) + log1p(exp(-|x|))
    return fmaxf(x, 0.0f) + log1pf(expf(-fabsf(x)));
}

__device__ __forceinline__ float4 f4add(const float4 a, const float4 b) {
    float4 r; r.x = a.x + b.x; r.y = a.y + b.y; r.z = a.z + b.z; r.w = a.w + b.w; return r;
}

// a.{x,y,z,w} += w.{x,y,z,w} * xs   (4 output rows, one broadcast input)
#define FMA4(a, w, xs)                                                        \
    a.x = fmaf((w).x, (xs), a.x); a.y = fmaf((w).y, (xs), a.y);               \
    a.z = fmaf((w).z, (xs), a.z); a.w = fmaf((w).w, (xs), a.w);

// pairwise tree-sum of P[0..15][gg] (float4 each)
#define PSUM16(P, gg)                                                         \
    f4add(f4add(f4add(f4add(P[0][gg],  P[1][gg]),  f4add(P[2][gg],  P[3][gg])),  \
                f4add(f4add(P[4][gg],  P[5][gg]),  f4add(P[6][gg],  P[7][gg]))), \
          f4add(f4add(f4add(P[8][gg],  P[9][gg]),  f4add(P[10][gg], P[11][gg])), \
                f4add(f4add(P[12][gg], P[13][gg]), f4add(P[14][gg], P[15][gg]))))

// One MLP eval for both samples.
// FMA-phase role (all 1024 threads): g = t&63, c = t>>6 (0..15).
//   L0/L1: thread computes rows {g, g+64, g+128, g+192} over k-slice
//          [c*4,+4) (L0) / [c*16,+16) (L1). Weights: sW0p (LDS, packed
//          float4 by row-group) and w1q (VGPR).
//   L2: thread computes row g over k-slice [c*16,+16), weights w2q (VGPR).
// Combine role (t<128): s = t>>6, gg = t&63 — b128 partial reads, 4 rows each.
#define FEVAL_CORE(PIN0, PIN1)                                                \
    {   /* layer 0 FMA */                                                     \
        const float4 x0 = *reinterpret_cast<const float4*>((PIN0) + c4);      \
        const float4 x1 = *reinterpret_cast<const float4*>((PIN1) + c4);      \
        float4 a0 = {0,0,0,0}, a1 = {0,0,0,0};                                \
        float4 w;                                                             \
        w = sW0p[c4 + 0][g]; FMA4(a0, w, x0.x) FMA4(a1, w, x1.x)              \
        w = sW0p[c4 + 1][g]; FMA4(a0, w, x0.y) FMA4(a1, w, x1.y)              \
        w = sW0p[c4 + 2][g]; FMA4(a0, w, x0.z) FMA4(a1, w, x1.z)              \
        w = sW0p[c4 + 3][g]; FMA4(a0, w, x0.w) FMA4(a1, w, x1.w)              \
        s_ps4[0][c][g] = a0; s_ps4[1][c][g] = a1;                             \
    }                                                                         \
    __syncthreads();                                                          \
    if (t < 128) {   /* h0 combine: 4 rows per thread, b128 reads */          \
        const int s = t >> 6, gg = t & 63;                                    \
        const float4 acc = PSUM16(s_ps4[s], gg);                              \
        s_h0[s][gg]       = softplus_jax(acc.x + s_b0[gg]);                   \
        s_h0[s][gg +  64] = softplus_jax(acc.y + s_b0[gg +  64]);             \
        s_h0[s][gg + 128] = softplus_jax(acc.z + s_b0[gg + 128]);             \
        s_h0[s][gg + 192] = softplus_jax(acc.w + s_b0[gg + 192]);             \
    }                                                                         \
    __syncthreads();                                                          \
    {   /* layer 1 FMA */                                                     \
        const float4* xx0 = reinterpret_cast<const float4*>(&s_h0[0][c16]);   \
        const float4* xx1 = reinterpret_cast<const float4*>(&s_h0[1][c16]);   \
        float4 a0 = {0,0,0,0}, a1 = {0,0,0,0};                                \
        float4 w;                                                             \
        _Pragma("unroll")                                                     \
        for (int j = 0; j < 4; ++j) {                                         \
            const float4 q0 = xx0[j], q1 = xx1[j];                            \
            w = w1q[4*j + 0]; FMA4(a0, w, q0.x) FMA4(a1, w, q1.x)             \
            w = w1q[4*j + 1]; FMA4(a0, w, q0.y) FMA4(a1, w, q1.y)             \
            w = w1q[4*j + 2]; FMA4(a0, w, q0.z) FMA4(a1, w, q1.z)             \
            w = w1q[4*j + 3]; FMA4(a0, w, q0.w) FMA4(a1, w, q1.w)             \
        }                                                                     \
        s_ps4[0][c][g] = a0; s_ps4[1][c][g] = a1;                             \
    }                                                                         \
    __syncthreads();                                                          \
    if (t < 128) {   /* h1 combine */                                         \
        const int s = t >> 6, gg = t & 63;                                    \
        const float4 acc = PSUM16(s_ps4[s], gg);                              \
        s_h1[s][gg]       = softplus_jax(acc.x + s_b1[gg]);                   \
        s_h1[s][gg +  64] = softplus_jax(acc.y + s_b1[gg +  64]);             \
        s_h1[s][gg + 128] = softplus_jax(acc.z + s_b1[gg + 128]);             \
        s_h1[s][gg + 192] = softplus_jax(acc.w + s_b1[gg + 192]);             \
    }                                                                         \
    __syncthreads();                                                          \
    {   /* layer 2 FMA: row g, k-slice [c16,+16), 2 acc chains */             \
        const float4* xx0 = reinterpret_cast<const float4*>(&s_h1[0][c16]);   \
        const float4* xx1 = reinterpret_cast<const float4*>(&s_h1[1][c16]);   \
        float e0 = 0.f, e1 = 0.f, f0 = 0.f, f1 = 0.f;                         \
        _Pragma("unroll")                                                     \
        for (int j = 0; j < 4; ++j) {                                         \
            const float4 q0 = xx0[j], q1 = xx1[j];                            \
            const float4 w = w2q[j];                                          \
            e0 = fmaf(w.x, q0.x, e0); e0 = fmaf(w.y, q0.y, e0);               \
            f0 = fmaf(w.z, q0.z, f0); f0 = fmaf(w.w, q0.w, f0);               \
            e1 = fmaf(w.x, q1.x, e1); e1 = fmaf(w.y, q1.y, e1);               \
            f1 = fmaf(w.z, q1.z, f1); f1 = fmaf(w.w, q1.w, f1);               \
        }                                                                     \
        s_ps2[0][c][g] = e0 + f0; s_ps2[1][c][g] = e1 + f1;                   \
    }                                                                         \
    __syncthreads();

#define KV_SUM(s)                                                             \
    (((((s_ps2[s][0][d] + s_ps2[s][1][d]) + (s_ps2[s][2][d] + s_ps2[s][3][d]))  \
     + ((s_ps2[s][4][d] + s_ps2[s][5][d]) + (s_ps2[s][6][d] + s_ps2[s][7][d]))) \
    + (((s_ps2[s][8][d] + s_ps2[s][9][d]) + (s_ps2[s][10][d] + s_ps2[s][11][d]))\
     + ((s_ps2[s][12][d] + s_ps2[s][13][d]) + (s_ps2[s][14][d] + s_ps2[s][15][d])))) \
    + s_b2[d])

__global__ __launch_bounds__(NTHR)
void ode_kernel(const float* __restrict__ ts, const float* __restrict__ y0,
                const float* __restrict__ W0, const float* __restrict__ b0,
                const float* __restrict__ W1, const float* __restrict__ b1,
                const float* __restrict__ W2, const float* __restrict__ b2,
                float* __restrict__ out)
{
    __shared__ __align__(16) float4 sW0p[DATA][64];          // 64 KB: [k][g] = rows {g,g+64,g+128,g+192}
    __shared__ __align__(16) float4 s_ps4[NSAMP][16][64];    // 32 KB: L0/L1 partials (reused)
    __shared__ __align__(16) float  s_ps2[NSAMP][16][DATA];  // 8 KB: L2 partials
    __shared__ __align__(16) float  s_h0[NSAMP][WIDTH];
    __shared__ __align__(16) float  s_h1[NSAMP][WIDTH];
    __shared__ __align__(16) float  s_y[NSAMP][DATA];
    __shared__ __align__(16) float  s_yst[NSAMP][DATA];
    __shared__ __align__(16) float  s_ynew[NSAMP][DATA];
    __shared__ __align__(16) float  s_k[NSAMP][6][DATA];
    __shared__ float s_b0[WIDTH], s_b1[WIDTH], s_b2[DATA];
    __shared__ float s_ts[TPTS];
    __shared__ float s_err[NSAMP];

    const int t   = threadIdx.x;
    const int g   = t & 63;
    const int c   = t >> 6;      // 0..15
    const int c4  = c * 4;
    const int c16 = c * 16;
    const int d   = t & 63;      // alias of g, for epilogue readability
    const int b   = blockIdx.x;

    // ---- prologue (one-time) ----
    // W1 rows {g,g+64,g+128,g+192}, k-slice [c16,+16) -> w1q (transposed pack)
    float4 w1q[16];
    {
        const float4* r0 = reinterpret_cast<const float4*>(W1 + (g      ) * WIDTH + c16);
        const float4* r1 = reinterpret_cast<const float4*>(W1 + (g +  64) * WIDTH + c16);
        const float4* r2 = reinterpret_cast<const float4*>(W1 + (g + 128) * WIDTH + c16);
        const float4* r3 = reinterpret_cast<const float4*>(W1 + (g + 192) * WIDTH + c16);
#pragma unroll
        for (int j = 0; j < 4; ++j) {
            const float4 q0 = r0[j], q1 = r1[j], q2 = r2[j], q3 = r3[j];
            w1q[4*j + 0] = make_float4(q0.x, q1.x, q2.x, q3.x);
            w1q[4*j + 1] = make_float4(q0.y, q1.y, q2.y, q3.y);
            w1q[4*j + 2] = make_float4(q0.z, q1.z, q2.z, q3.z);
            w1q[4*j + 3] = make_float4(q0.w, q1.w, q2.w, q3.w);
        }
    }
    // W2 row g, k-slice [c16,+16) -> w2q
    float4 w2q[4];
    {
        const float4* r2p = reinterpret_cast<const float4*>(W2 + g * WIDTH + c16);
#pragma unroll
        for (int j = 0; j < 4; ++j) w2q[j] = r2p[j];
    }
    // W0 packed to LDS: sW0p[k][g] = {W0[g][k], W0[g+64][k], W0[g+128][k], W0[g+192][k]}
    for (int i = t; i < DATA * DATA; i += NTHR) {   // 4096 -> 4 iters
        const int kk = i >> 6, gg = i & 63;
        float4 w;
        w.x = W0[(gg      ) * DATA + kk];
        w.y = W0[(gg +  64) * DATA + kk];
        w.z = W0[(gg + 128) * DATA + kk];
        w.w = W0[(gg + 192) * DATA + kk];
        sW0p[kk][gg] = w;   // lanes write consecutive float4s: conflict-free
    }
    if (t < WIDTH) { s_b0[t] = b0[t]; s_b1[t] = b1[t]; }
    if (t < DATA)  { s_b2[t] = b2[t]; }
    if (t < TPTS)  { s_ts[t] = ts[t]; }
    if (t < NSAMP * DATA) {
        const int s = t >> 6;
        const float v = y0[(b * NSAMP + s) * DATA + d];
        s_y[s][d] = v;
        out[(size_t)(b * NSAMP + s) * TPTS * DATA + d] = v;
    }
    __syncthreads();

    // per-sample control state, replicated identically in every thread
    float dtv0 = s_ts[1] - s_ts[0];
    float dtv1 = dtv0;

    for (int iv = 0; iv < TPTS - 1; ++iv) {
        const float t1v = s_ts[iv + 1];
        float tc0 = s_ts[iv], tc1 = tc0;

        for (int ss = 0; ss < MAXSUB; ++ss) {
            const float rem0 = t1v - tc0, rem1 = t1v - tc1;
            const bool done0 = rem0 <= 1e-6f, done1 = rem1 <= 1e-6f;
            if (done0 && done1) break;  // remaining reference iters are exact identities
            const float dtc0 = done0 ? dtv0 : fminf(dtv0, rem0);
            const float dtc1 = done1 ? dtv1 : fminf(dtv1, rem1);

            // ---- stage 1
            FEVAL_CORE(&s_y[0][0], &s_y[1][0])
            if (t < 128) {
                const int s = t >> 6;
                const float dtc_s = (s == 0) ? dtc0 : dtc1;
                const float kv = KV_SUM(s);
                s_k[s][0][d] = kv;
                s_yst[s][d] = s_y[s][d] + dtc_s * (A21 * kv);
            }
            __syncthreads();
            // ---- stage 2
            FEVAL_CORE(&s_yst[0][0], &s_yst[1][0])
            if (t < 128) {
                const int s = t >> 6;
                const float dtc_s = (s == 0) ? dtc0 : dtc1;
                const float kv = KV_SUM(s);
                s_k[s][1][d] = kv;
                s_yst[s][d] = s_y[s][d] + dtc_s * (A31 * s_k[s][0][d] + A32 * kv);
            }
            __syncthreads();
            // ---- stage 3
            FEVAL_CORE(&s_yst[0][0], &s_yst[1][0])
            if (t < 128) {
                const int s = t >> 6;
                const float dtc_s = (s == 0) ? dtc0 : dtc1;
                const float kv = KV_SUM(s);
                s_k[s][2][d] = kv;
                s_yst[s][d] = s_y[s][d] + dtc_s * (A41 * s_k[s][0][d] + A42 * s_k[s][1][d] + A43 * kv);
            }
            __syncthreads();
            // ---- stage 4
            FEVAL_CORE(&s_yst[0][0], &s_yst[1][0])
            if (t < 128) {
                const int s = t >> 6;
                const float dtc_s = (s == 0) ? dtc0 : dtc1;
                const float kv = KV_SUM(s);
                s_k[s][3][d] = kv;
                s_yst[s][d] = s_y[s][d] + dtc_s * (A51 * s_k[s][0][d] + A52 * s_k[s][1][d]
                                                 + A53 * s_k[s][2][d] + A54 * kv);
            }
            __syncthreads();
            // ---- stage 5
            FEVAL_CORE(&s_yst[0][0], &s_yst[1][0])
            if (t < 128) {
                const int s = t >> 6;
                const float dtc_s = (s == 0) ? dtc0 : dtc1;
                const float kv = KV_SUM(s);
                s_k[s][4][d] = kv;
                s_yst[s][d] = s_y[s][d] + dtc_s * (A61 * s_k[s][0][d] + A62 * s_k[s][1][d]
                                                 + A63 * s_k[s][2][d] + A64 * s_k[s][3][d] + A65 * kv);
            }
            __syncthreads();
            // ---- stage 6 -> y_new
            FEVAL_CORE(&s_yst[0][0], &s_yst[1][0])
            if (t < 128) {
                const int s = t >> 6;
                const float dtc_s = (s == 0) ? dtc0 : dtc1;
                const float kv = KV_SUM(s);
                s_k[s][5][d] = kv;
                s_ynew[s][d] = s_y[s][d] + dtc_s * (B1c * s_k[s][0][d] + B2c * s_k[s][1][d]
                                                  + B3c * s_k[s][2][d] + B4c * s_k[s][3][d]
                                                  + B5c * s_k[s][4][d] + B6c * kv);
            }
            __syncthreads();
            // ---- stage 7 (error estimate only)
            FEVAL_CORE(&s_ynew[0][0], &s_ynew[1][0])
            if (t < 128) {
                const int s = t >> 6;
                const float dtc_s = (s == 0) ? dtc0 : dtc1;
                const float kv = KV_SUM(s);  // k7
                const float e = dtc_s * (E1c * s_k[s][0][d] + E2c * s_k[s][1][d]
                                       + E3c * s_k[s][2][d] + E4c * s_k[s][3][d]
                                       + E5c * s_k[s][4][d] + E6c * s_k[s][5][d] + E7c * kv);
                const float yv = s_y[s][d], ynv = s_ynew[s][d];
                const float sc = ATOLc + RTOLc * fmaxf(fabsf(yv), fabsf(ynv));
                const float rr2 = e / sc;
                float v = rr2 * rr2;
#pragma unroll
                for (int off = 32; off > 0; off >>= 1) v += __shfl_xor(v, off, 64);
                if (d == 0) s_err[s] = v;
            }
            __syncthreads();

            // ---- controller (replicated; identical in every thread)
            const float en0 = sqrtf(s_err[0] * (1.0f / DATA));
            const float en1 = sqrtf(s_err[1] * (1.0f / DATA));
            const bool acc0 = en0 <= 1.0f, acc1 = en1 <= 1.0f;
            float f0 = fminf(fmaxf(SAFETYc * powf(fmaxf(en0, 1e-10f), -0.2f), FMINc), FMAXc);
            float f1 = fminf(fmaxf(SAFETYc * powf(fmaxf(en1, 1e-10f), -0.2f), FMINc), FMAXc);
            const bool step0 = acc0 && !done0, step1 = acc1 && !done1;
            if (t < 128) {
                const int s = t >> 6;
                const bool st = (s == 0) ? step0 : step1;
                if (st) s_y[s][d] = s_ynew[s][d];
            }
            if (step0) tc0 += dtc0;
            if (step1) tc1 += dtc1;
            dtv0 = done0 ? dtv0 : dtc0 * f0;
            dtv1 = done1 ? dtv1 : dtc1 * f1;
            __syncthreads();
        }

        if (t < 128) {
            const int s = t >> 6;
            out[(size_t)(b * NSAMP + s) * TPTS * DATA + (size_t)(iv + 1) * DATA + d] = s_y[s][d];
        }
        // no barrier needed: next substep reads s_y only after its own barriers
    }
}

extern "C" void kernel_launch(void* const* d_in, const int* in_sizes, int n_in,
                              void* d_out, int out_size, void* d_ws, size_t ws_size,
                              hipStream_t stream)
{
    const float* ts = (const float*)d_in[0];
    const float* y0 = (const float*)d_in[1];
    const float* W0 = (const float*)d_in[2];
    const float* b0 = (const float*)d_in[3];
    const float* W1 = (const float*)d_in[4];
    const float* b1 = (const float*)d_in[5];
    const float* W2 = (const float*)d_in[6];
    const float* b2 = (const float*)d_in[7];
    float* out = (float*)d_out;

    ode_kernel<<<NBLK, NTHR, 0, stream>>>(ts, y0, W0, b0, W1, b1, W2, b2, out);
}